// Round 8
// baseline (305.195 us; speedup 1.0000x reference)
//
#include <hip/hip_runtime.h>

typedef __attribute__((ext_vector_type(8))) short short8;
typedef __attribute__((ext_vector_type(4))) float floatx4;
typedef __attribute__((address_space(3))) void lvoid;
typedef const __attribute__((address_space(1))) void gvoid;

#define LOG2E 1.44269504088896340736f

__device__ __forceinline__ ushort f2bf(float f) {
  union { float f; unsigned u; } v; v.f = f;
  unsigned r = v.u + 0x7fffu + ((v.u >> 16) & 1u);
  return (ushort)(r >> 16);
}

__device__ __forceinline__ void gld16(const void* g, void* l) {
  __builtin_amdgcn_global_load_lds((gvoid*)g, (lvoid*)l, 16, 0, 0);
}

// ---------------- prep: X fp32 -> bf16 -------------------------------------
__global__ __launch_bounds__(256) void k_prep_x(const float* __restrict__ X,
                                                ushort* __restrict__ Xb) {
  const size_t i = ((size_t)blockIdx.x * 256 + threadIdx.x) * 8;
  float4 v0 = *(const float4*)(X + i);
  float4 v1 = *(const float4*)(X + i + 4);
  ushort u[8] = {f2bf(v0.x), f2bf(v0.y), f2bf(v0.z), f2bf(v0.w),
                 f2bf(v1.x), f2bf(v1.y), f2bf(v1.z), f2bf(v1.w)};
  *(uint4*)(Xb + i) = *(uint4*)u;
}

// ---------------- prep: W fp32 [K][N] -> bf16 transposed [N][K] ------------
__global__ __launch_bounds__(256) void k_prep_wt(
    const float* __restrict__ W0, const float* __restrict__ W1,
    const float* __restrict__ W2, const float* __restrict__ W3,
    ushort* __restrict__ T0, ushort* __restrict__ T1,
    ushort* __restrict__ T2, ushort* __restrict__ T3) {
  __shared__ ushort T[64][66];
  const int z = blockIdx.z;
  const float* W = z == 0 ? W0 : (z == 1 ? W1 : (z == 2 ? W2 : W3));
  ushort* Wt = z == 0 ? T0 : (z == 1 ? T1 : (z == 2 ? T2 : T3));
  const int kb = blockIdx.x * 64, nb = blockIdx.y * 64;
  const int t = threadIdx.x, r = t >> 2, c0 = (t & 3) * 16;
  const float* src = W + (size_t)(kb + r) * 1024 + nb + c0;
  #pragma unroll
  for (int i = 0; i < 4; i++) {
    float4 a = ((const float4*)src)[i];
    T[r][c0 + i*4 + 0] = f2bf(a.x); T[r][c0 + i*4 + 1] = f2bf(a.y);
    T[r][c0 + i*4 + 2] = f2bf(a.z); T[r][c0 + i*4 + 3] = f2bf(a.w);
  }
  __syncthreads();
  ushort u[16];
  #pragma unroll
  for (int j = 0; j < 16; j++) u[j] = T[c0 + j][r];
  ushort* dst = Wt + (size_t)(nb + r) * 1024 + kb + c0;
  ((uint4*)dst)[0] = ((uint4*)u)[0];
  ((uint4*)dst)[1] = ((uint4*)u)[1];
}

// ---------------- GEMM loop: 2-phase prefetch, double-buffered LDS ---------
#define GEMM_LOOP(Aptr, BTptr, BFptr)                                          \
  constexpr int LDB = PREPPED ? 32 : 40;                                       \
  __shared__ __align__(16) ushort As[2][128 * 32];                             \
  __shared__ __align__(16) ushort Bs[2][128 * LDB];                            \
  const int tid = threadIdx.x, l = tid & 63, w = tid >> 6;                     \
  const int wm = w >> 1, wn = w & 1, lr = l & 15, lk = l >> 4;                 \
  const int m0 = blockIdx.y * 128, n0 = blockIdx.x * 128;                      \
  const int srow = l >> 2;                                                     \
  const int scol = ((l & 3) ^ ((l >> 3) & 3)) * 8;                             \
  const int c0 = w * 2;                                                        \
  const int xchunk = (lk ^ ((lr >> 1) & 3)) * 8;                               \
  const int bk = tid >> 3, bn = (tid & 7) * 16;                                \
  floatx4 acc[4][4] = {};                                                      \
  /* prologue: stage kt=0 into buffer 0 */                                     \
  _Pragma("unroll")                                                            \
  for (int i = 0; i < 2; i++) {                                                \
    const int c = c0 + i;                                                      \
    gld16(Aptr + (size_t)(m0 + c*16 + srow) * 1024 + scol, &As[0][c*512]);     \
    if constexpr (PREPPED)                                                     \
      gld16(BTptr + (size_t)(n0 + c*16 + srow) * 1024 + scol, &Bs[0][c*512]);  \
  }                                                                            \
  if constexpr (!PREPPED) {                                                    \
    const float* src = BFptr + (size_t)bk * 1024 + n0 + bn;                    \
    float vb[16];                                                              \
    _Pragma("unroll")                                                          \
    for (int i = 0; i < 4; i++) ((float4*)vb)[i] = ((const float4*)src)[i];    \
    _Pragma("unroll")                                                          \
    for (int i = 0; i < 16; i++) Bs[0][(bn + i) * 40 + bk] = f2bf(vb[i]);      \
  }                                                                            \
  for (int kt = 0; kt < 1024; kt += 32) {                                      \
    const int cur = (kt >> 5) & 1, nxt = cur ^ 1;                              \
    __syncthreads(); /* buf[cur] staged; prev reads done (lgkm+vm drained) */  \
    float vbn[16];                                                             \
    if (kt + 32 < 1024) {                                                      \
      _Pragma("unroll")                                                        \
      for (int i = 0; i < 2; i++) {                                            \
        const int c = c0 + i;                                                  \
        gld16(Aptr + (size_t)(m0 + c*16 + srow) * 1024 + kt + 32 + scol,       \
              &As[nxt][c*512]);                                                \
        if constexpr (PREPPED)                                                 \
          gld16(BTptr + (size_t)(n0 + c*16 + srow) * 1024 + kt + 32 + scol,    \
                &Bs[nxt][c*512]);                                              \
      }                                                                        \
      if constexpr (!PREPPED) {                                                \
        const float* src = BFptr + (size_t)(kt + 32 + bk) * 1024 + n0 + bn;    \
        _Pragma("unroll")                                                      \
        for (int i = 0; i < 4; i++)                                            \
          ((float4*)vbn)[i] = ((const float4*)src)[i];                         \
      }                                                                        \
    }                                                                          \
    short8 af[4], bfr[4];                                                      \
    _Pragma("unroll")                                                          \
    for (int f = 0; f < 4; f++) {                                              \
      af[f] = *(const short8*)&As[cur][(wm*64 + f*16 + lr) * 32 + xchunk];     \
      if constexpr (PREPPED)                                                   \
        bfr[f] = *(const short8*)&Bs[cur][(wn*64 + f*16 + lr) * 32 + xchunk];  \
      else                                                                     \
        bfr[f] = *(const short8*)&Bs[cur][(wn*64 + f*16 + lr) * 40 + lk*8];    \
    }                                                                          \
    __builtin_amdgcn_s_setprio(1);                                             \
    _Pragma("unroll")                                                          \
    for (int i = 0; i < 4; i++)                                                \
      _Pragma("unroll")                                                        \
      for (int j = 0; j < 4; j++)                                              \
        acc[i][j] = __builtin_amdgcn_mfma_f32_16x16x32_bf16(af[i], bfr[j],     \
                                                            acc[i][j], 0,0,0);\
    __builtin_amdgcn_s_setprio(0);                                             \
    if constexpr (!PREPPED) {                                                  \
      if (kt + 32 < 1024) { /* write-late (T14): vbn ready under MFMA */       \
        _Pragma("unroll")                                                      \
        for (int i = 0; i < 16; i++)                                           \
          Bs[nxt][(bn + i) * 40 + bk] = f2bf(vbn[i]);                          \
      }                                                                        \
    }                                                                          \
  }

// Projection GEMM. z=0: Q (scaled 1/8, [b,h,s,hd]); z=1: K ([b,h,s,hd]);
// z=2: V written TRANSPOSED [b,h,hd,s].
template <bool PREPPED>
__global__ __launch_bounds__(256) void k_proj(
    const ushort* __restrict__ Xb,
    const ushort* __restrict__ Wtq, const ushort* __restrict__ Wtk,
    const ushort* __restrict__ Wtv,
    const float* __restrict__ Wfq, const float* __restrict__ Wfk,
    const float* __restrict__ Wfv,
    ushort* __restrict__ Qo, ushort* __restrict__ Ko, ushort* __restrict__ Vo)
{
  const int z = blockIdx.z;
  const ushort* Bt = PREPPED ? (z == 0 ? Wtq : (z == 1 ? Wtk : Wtv)) : nullptr;
  const float*  Bf = PREPPED ? nullptr : (z == 0 ? Wfq : (z == 1 ? Wfk : Wfv));
  ushort* Out = z == 0 ? Qo : (z == 1 ? Ko : Vo);
  const float scale = z == 0 ? 0.125f : 1.0f;
  GEMM_LOOP(Xb, Bt, Bf)
  if (z == 2) {
    // V: write transposed [bh][hd][s]; 4 consecutive s per 8B store
    #pragma unroll
    for (int i = 0; i < 4; i++) {
      const int m = m0 + wm*64 + i*16 + lk*4;
      const int bb = m >> 11, s = m & 2047;
      #pragma unroll
      for (int j = 0; j < 4; j++) {
        const int n = n0 + wn*64 + j*16 + lr;
        const int h = n >> 6, hd = n & 63;
        ushort u4[4];
        #pragma unroll
        for (int r = 0; r < 4; r++) u4[r] = f2bf(acc[i][j][r]);
        *(uint2*)(Out + (((size_t)(bb*16 + h)) * 64 + hd) * 2048 + s) = *(uint2*)u4;
      }
    }
  } else {
    #pragma unroll
    for (int i = 0; i < 4; i++) {
      #pragma unroll
      for (int j = 0; j < 4; j++) {
        const int n = n0 + wn*64 + j*16 + lr;
        const int h = n >> 6, hd = n & 63;
        #pragma unroll
        for (int r = 0; r < 4; r++) {
          const int m = m0 + wm*64 + i*16 + lk*4 + r;
          const int bb = m >> 11, s = m & 2047;
          Out[(((size_t)(bb*16 + h)) * 2048 + s) * 64 + hd] = f2bf(acc[i][j][r] * scale);
        }
      }
    }
  }
}

// Output GEMM: fp32 out [8192][1024] = AO(bf16) @ Wo
template <bool PREPPED>
__global__ __launch_bounds__(256) void k_out(
    const ushort* __restrict__ A, const ushort* __restrict__ Wt,
    const float* __restrict__ Wf, float* __restrict__ Out)
{
  GEMM_LOOP(A, Wt, Wf)
  #pragma unroll
  for (int i = 0; i < 4; i++) {
    #pragma unroll
    for (int j = 0; j < 4; j++) {
      const int n = n0 + wn*64 + j*16 + lr;
      #pragma unroll
      for (int r = 0; r < 4; r++) {
        const int m = m0 + wm*64 + i*16 + lk*4 + r;
        Out[(size_t)m * 1024 + n] = acc[i][j][r];
      }
    }
  }
}

// ---------------- Flash attention, paired q-tiles {p, 31-p} ----------------
// Swapped QK^T (S^T layout), per-lane softmax, P redistributed fully
// in-register via bpermute (no LDS round-trip, no sched fences).
// LDS = 2*8K (K) + 2*8K (V) = 32768 B -> 5 blocks/CU.
__global__ __launch_bounds__(256) void k_attn(
    const ushort* __restrict__ Q, const ushort* __restrict__ K,
    const ushort* __restrict__ V, const int* __restrict__ amask,
    ushort* __restrict__ AO)
{
  __shared__ __align__(16) ushort Kl[2][64 * 64];  // XOR-swizzled
  __shared__ __align__(16) ushort Vl[2][64 * 64];  // V^T tile, XOR-swizzled

  const int tid = threadIdx.x, l = tid & 63, w = tid >> 6;
  const int lr = l & 15, lk = l >> 4;
  const int g = blockIdx.x;
  const int swz = (g & 7) * 128 + (g >> 3);        // bijective XCD chunking
  const int p = swz & 15, bh = swz >> 4;
  const int b = bh >> 4, h = bh & 15;
  const int qA0 = p * 64, qB0 = (31 - p) * 64;

  const ushort* Qbh = Q + (size_t)bh * 2048 * 64;
  const ushort* Kbh = K + (size_t)bh * 2048 * 64;
  const ushort* Vbh = V + (size_t)bh * 64 * 2048;  // transposed [hd][s]

  const int qrA = qA0 + w*16 + lr, qrB = qB0 + w*16 + lr;
  short8 aqA0 = *(const short8*)(Qbh + (size_t)qrA * 64 + lk*8);
  short8 aqA1 = *(const short8*)(Qbh + (size_t)qrA * 64 + 32 + lk*8);
  short8 aqB0 = *(const short8*)(Qbh + (size_t)qrB * 64 + lk*8);
  short8 aqB1 = *(const short8*)(Qbh + (size_t)qrB * 64 + 32 + lk*8);

  floatx4 oA[4] = {}, oB[4] = {};
  float mmA = -1e30f, llA = 0.f, mmB = -1e30f, llB = 0.f;

  // staging lane addresses (chunk-XOR swizzled source)
  const int krow = l >> 3;
  const int kcol = ((l & 7) ^ krow) * 8;

  // P-redistribution source lanes (derived from fragment maps, see notes):
  // lane (lr,lk) pulls chunk words from s_a = lr + 32*(lk&1), s_b = s_a+16,
  // selecting pk[lk>>1] / pk[2+(lk>>1)].
  const int sa_ = lr + ((lk & 1) << 5);
  const int sb_ = sa_ + 16;
  const bool hi_ = lk >= 2;

  const int kend = 31 - p;
  const int amb = b * 2048;
  int kv0 = 0;

  auto stage = [&](int bi, int kv) {
    #pragma unroll
    for (int i = 0; i < 2; i++) {
      const int c = w*2 + i;
      gld16(Kbh + (size_t)(kv + c*8 + krow) * 64 + kcol, &Kl[bi][c*512]);
      gld16(Vbh + (size_t)(c*8 + krow) * 2048 + kv + kcol, &Vl[bi][c*512]);
    }
  };

  // per-lane softmax: lane (lr,lk) owns q-row = base + w*16 + lr
  auto process = [&](const short8& q0f, const short8& q1f, floatx4* o,
                     float& mm, float& ll, int qbase, bool diag,
                     float mval, bool allv, int cur) {
    // S^T = K Q^T: sa[f][r] = S[q = qbase+w*16+lr][kv = kv0 + f*16 + lk*4 + r]
    floatx4 sa[4] = {};
    __builtin_amdgcn_s_setprio(1);
    #pragma unroll
    for (int f = 0; f < 4; f++) {
      const int rb = f*16 + lr;
      const int cs = (rb & 7) * 8;
      short8 k0 = *(const short8*)&Kl[cur][rb*64 + ((lk*8) ^ cs)];
      short8 k1 = *(const short8*)&Kl[cur][rb*64 + (((4+lk)*8) ^ cs)];
      sa[f] = __builtin_amdgcn_mfma_f32_16x16x32_bf16(k0, q0f, sa[f], 0,0,0);
      sa[f] = __builtin_amdgcn_mfma_f32_16x16x32_bf16(k1, q1f, sa[f], 0,0,0);
    }
    __builtin_amdgcn_s_setprio(0);
    // key mask: rare non-uniform path only
    if (!allv) {
      #pragma unroll
      for (int f = 0; f < 4; f++)
        #pragma unroll
        for (int r = 0; r < 4; r++)
          sa[f][r] += __shfl(mval, f*16 + lk*4 + r, 64);
    }
    // causal: only on diagonal tile
    if (diag) {
      const int q = qbase + w*16 + lr;
      #pragma unroll
      for (int f = 0; f < 4; f++)
        #pragma unroll
        for (int r = 0; r < 4; r++)
          if (kv0 + f*16 + lk*4 + r > q) sa[f][r] = -1e30f;
    }
    // row max (one q per lane; combine 4 lk-lanes sharing lr)
    float mx = sa[0][0];
    #pragma unroll
    for (int f = 0; f < 4; f++)
      #pragma unroll
      for (int r = 0; r < 4; r++) mx = fmaxf(mx, sa[f][r]);
    mx = fmaxf(mx, __shfl_xor(mx, 16, 64));
    mx = fmaxf(mx, __shfl_xor(mx, 32, 64));
    // defer-max (T13)
    if (!__all(mx <= mm + 8.f)) {
      const float pm = fmaxf(mm, mx);
      const float scl = __builtin_exp2f((mm - pm) * LOG2E);
      mm = pm;
      ll *= scl;
      float sclo[4];
      #pragma unroll
      for (int r = 0; r < 4; r++) sclo[r] = __shfl(scl, lk*4 + r, 64);
      #pragma unroll
      for (int f = 0; f < 4; f++)
        #pragma unroll
        for (int r = 0; r < 4; r++) o[f][r] *= sclo[r];
    }
    // P = exp2(S*log2e - mm*log2e), row sum
    const float nm = mm * LOG2E;
    float rs = 0.f;
    #pragma unroll
    for (int f = 0; f < 4; f++)
      #pragma unroll
      for (int r = 0; r < 4; r++) {
        float pv = __builtin_exp2f(__builtin_fmaf(sa[f][r], LOG2E, -nm));
        sa[f][r] = pv;
        rs += pv;
      }
    rs += __shfl_xor(rs, 16, 64);
    rs += __shfl_xor(rs, 32, 64);
    ll += rs;
    // pack P to bf16 pairs: pk[f][h] = (kv = f*16+lk*4+2h, +1)
    unsigned pk[4][2];
    #pragma unroll
    for (int f = 0; f < 4; f++) {
      asm("v_cvt_pk_bf16_f32 %0, %1, %2" : "=v"(pk[f][0])
          : "v"(sa[f][0]), "v"(sa[f][1]));
      asm("v_cvt_pk_bf16_f32 %0, %1, %2" : "=v"(pk[f][1])
          : "v"(sa[f][2]), "v"(sa[f][3]));
    }
    // in-register P redistribution -> A-frags (16 bpermute + 8 cndmask)
    union { unsigned u[4]; short8 s; } ap0, ap1;
    {
      unsigned q00 = __shfl(pk[0][0], sa_), q10 = __shfl(pk[1][0], sa_);
      unsigned q01 = __shfl(pk[0][1], sa_), q11 = __shfl(pk[1][1], sa_);
      unsigned q02 = __shfl(pk[0][0], sb_), q12 = __shfl(pk[1][0], sb_);
      unsigned q03 = __shfl(pk[0][1], sb_), q13 = __shfl(pk[1][1], sb_);
      ap0.u[0] = hi_ ? q10 : q00; ap0.u[1] = hi_ ? q11 : q01;
      ap0.u[2] = hi_ ? q12 : q02; ap0.u[3] = hi_ ? q13 : q03;
      unsigned r00 = __shfl(pk[2][0], sa_), r10 = __shfl(pk[3][0], sa_);
      unsigned r01 = __shfl(pk[2][1], sa_), r11 = __shfl(pk[3][1], sa_);
      unsigned r02 = __shfl(pk[2][0], sb_), r12 = __shfl(pk[3][0], sb_);
      unsigned r03 = __shfl(pk[2][1], sb_), r13 = __shfl(pk[3][1], sb_);
      ap1.u[0] = hi_ ? r10 : r00; ap1.u[1] = hi_ ? r11 : r01;
      ap1.u[2] = hi_ ? r12 : r02; ap1.u[3] = hi_ ? r13 : r03;
    }
    __builtin_amdgcn_s_setprio(1);
    #pragma unroll
    for (int f = 0; f < 4; f++) {
      const int rb = f*16 + lr;
      const int cs = (rb & 7) * 8;
      short8 bv0 = *(const short8*)&Vl[cur][rb*64 + ((lk*8) ^ cs)];
      short8 bv1 = *(const short8*)&Vl[cur][rb*64 + (((4+lk)*8) ^ cs)];
      o[f] = __builtin_amdgcn_mfma_f32_16x16x32_bf16(ap0.s, bv0, o[f], 0,0,0);
      o[f] = __builtin_amdgcn_mfma_f32_16x16x32_bf16(ap1.s, bv1, o[f], 0,0,0);
    }
    __builtin_amdgcn_s_setprio(0);
  };

  stage(0, 0);  // prologue
  for (int t = 0; t <= kend; t++) {
    kv0 = t * 64;
    const int am = amask[amb + kv0 + l];  // issue early; barrier hides latency
    __syncthreads();  // buf[t&1] staged; prev tile's LDS reads done
    if (t < kend) stage((t + 1) & 1, kv0 + 64);
    const bool allv = __all(am != 0);
    const float mval = am ? 0.f : -1e30f;
    const int cur = t & 1;
    process(aqB0, aqB1, oB, mmB, llB, qB0, t == kend, mval, allv, cur);
    if (t <= p) process(aqA0, aqA1, oA, mmA, llA, qA0, t == p, mval, allv, cur);
  }

  // epilogue: o rows are q = lk*4+r; fetch inv from the lane owning that q
  const float invA = llA > 0.f ? 1.0f / llA : 0.f;
  const float invB = llB > 0.f ? 1.0f / llB : 0.f;
  float ivA[4], ivB[4];
  #pragma unroll
  for (int r = 0; r < 4; r++) {
    ivA[r] = __shfl(invA, lk*4 + r, 64);
    ivB[r] = __shfl(invB, lk*4 + r, 64);
  }
  #pragma unroll
  for (int r = 0; r < 4; r++) {
    const int sA = qA0 + w*16 + lk*4 + r;
    const int sB = qB0 + w*16 + lk*4 + r;
    const size_t baseA = ((size_t)b * 2048 + sA) * 1024 + h * 64;
    const size_t baseB = ((size_t)b * 2048 + sB) * 1024 + h * 64;
    #pragma unroll
    for (int f = 0; f < 4; f++) {
      AO[baseA + f*16 + lr] = f2bf(oA[f][r] * ivA[r]);
      AO[baseB + f*16 + lr] = f2bf(oB[f][r] * ivB[r]);
    }
  }
}

extern "C" void kernel_launch(void* const* d_in, const int* in_sizes, int n_in,
                              void* d_out, int out_size, void* d_ws, size_t ws_size,
                              hipStream_t stream) {
  const float* x     = (const float*)d_in[0];
  const int*   amask = (const int*)d_in[1];
  const float* Wq    = (const float*)d_in[2];
  const float* Wk    = (const float*)d_in[3];
  const float* Wv    = (const float*)d_in[4];
  const float* Wo    = (const float*)d_in[5];
  float* out = (float*)d_out;

  const size_t NEL = (size_t)4 * 2048 * 1024;   // 8,388,608 elems (16 MB bf16)
  const size_t WEL = (size_t)1024 * 1024;       // 2 MB bf16

  dim3 blk(256);
  const bool prepped = ws_size >= (size_t)76 * 1024 * 1024;

  if (prepped) {
    ushort* Xb  = (ushort*)d_ws;
    ushort* Wtq = Xb + NEL;
    ushort* Wtk = Wtq + WEL;
    ushort* Wtv = Wtk + WEL;
    ushort* Wto = Wtv + WEL;
    ushort* Qb  = Wto + WEL;
    ushort* Kb  = Qb + NEL;
    ushort* Vb  = Kb + NEL;
    ushort* AO  = Xb;  // Xb dead after k_proj

    k_prep_x<<<4096, blk, 0, stream>>>(x, Xb);
    k_prep_wt<<<dim3(16, 16, 4), blk, 0, stream>>>(Wq, Wk, Wv, Wo,
                                                   Wtq, Wtk, Wtv, Wto);
    k_proj<true><<<dim3(8, 64, 3), blk, 0, stream>>>(
        Xb, Wtq, Wtk, Wtv, nullptr, nullptr, nullptr, Qb, Kb, Vb);
    k_attn<<<dim3(1024), blk, 0, stream>>>(Qb, Kb, Vb, amask, AO);
    k_out<true><<<dim3(8, 64), blk, 0, stream>>>(AO, Wto, nullptr, out);
  } else {
    ushort* Xb = (ushort*)d_ws;
    ushort* Qb = Xb + NEL;
    ushort* Kb = Qb + NEL;
    ushort* Vb = Kb + NEL;
    ushort* AO = Xb;

    k_prep_x<<<4096, blk, 0, stream>>>(x, Xb);
    k_proj<false><<<dim3(8, 64, 3), blk, 0, stream>>>(
        Xb, nullptr, nullptr, nullptr, Wq, Wk, Wv, Qb, Kb, Vb);
    k_attn<<<dim3(1024), blk, 0, stream>>>(Qb, Kb, Vb, amask, AO);
    k_out<false><<<dim3(8, 64), blk, 0, stream>>>(AO, nullptr, Wo, out);
  }
}